// Round 1
// baseline (47379.959 us; speedup 1.0000x reference)
//
#include <hip/hip_runtime.h>
#include <math.h>

// Problem constants
#define NB 64      // batch
#define NT 512     // timesteps
#define NDIN 256   // input dim
#define NH 1024    // hidden
#define NG 4096    // 4*NH gate width
#define NDOUT 256  // output dim
#define KT 128     // K-chunk staged in LDS
#define LSTR 132   // LDS row stride in floats (128 + 4 pad: bank-spread + 16B align)

__device__ __forceinline__ float sigf(float v) { return 1.0f / (1.0f + expf(-v)); }

__global__ void zero_kernel(float* __restrict__ p, int n) {
    int i = blockIdx.x * 256 + threadIdx.x;
    if (i < n) p[i] = 0.0f;
}

// gates==1: blocks [0,256) do LSTM gate GEMM + cell update for step t
//           blocks [256,272) do the Dense+ReLU projection of h_t (output row t-1)
// gates==0: all blocks do projection of h_in (output row t)  [tail launch]
__global__ __launch_bounds__(256) void lstm_step(
    const float* __restrict__ x, const float* __restrict__ Wx,
    const float* __restrict__ Wh, const float* __restrict__ bias,
    const float* __restrict__ Wo, const float* __restrict__ bo,
    const float* __restrict__ h_in, float* __restrict__ h_out,
    float* __restrict__ cst, float* __restrict__ out,
    int t, int gates)
{
    __shared__ float inp[NB * LSTR];   // staged input rows [64][KT] (padded)
    __shared__ float zs[16 * 65];      // z exchange for gate combine

    const int tid = threadIdx.x;
    const int bid = blockIdx.x;
    const int nl = tid & 15;   // column-lane within tile
    const int mg = tid >> 4;   // row-group 0..15

    const bool is_proj = gates ? (bid >= 256) : true;

    if (!is_proj) {
        // ---- gate block: computes z[:, {g*1024 + j0+q}] for g=0..3, q=0..3 ----
        const int j0 = bid * 4;                       // h-column base (0..1020)
        const int wcol = (nl >> 2) * NH + j0 + (nl & 3);  // raw gate-space column
        float acc0 = 0.f, acc1 = 0.f, acc2 = 0.f, acc3 = 0.f;

        for (int ci = 0; ci < 10; ++ci) {             // 10 * 128 = 1280 = DIN + H
            const int kbase = ci * KT;
            const bool isx = (kbase < NDIN);
            // cooperative stage of input rows [64][128] into LDS (float4, coalesced)
            #pragma unroll
            for (int i = 0; i < 8; ++i) {
                const int idx = i * 256 + tid;
                const int row = idx >> 5;
                const int c4 = (idx & 31) * 4;
                const float* src = isx
                    ? (x + ((size_t)row * NT + t) * NDIN + kbase + c4)
                    : (h_in + (size_t)row * NH + (kbase - NDIN) + c4);
                *(float4*)&inp[row * LSTR + c4] = *(const float4*)src;
            }
            __syncthreads();

            const float* Wp = isx ? (Wx + (size_t)kbase * NG + wcol)
                                  : (Wh + (size_t)(kbase - NDIN) * NG + wcol);
            for (int kk = 0; kk < KT; kk += 8) {
                float w[8];
                #pragma unroll
                for (int u = 0; u < 8; ++u) w[u] = Wp[(size_t)(kk + u) * NG];
                #pragma unroll
                for (int u = 0; u < 8; u += 4) {
                    float4 a0 = *(const float4*)&inp[(mg +  0) * LSTR + kk + u];
                    float4 a1 = *(const float4*)&inp[(mg + 16) * LSTR + kk + u];
                    float4 a2 = *(const float4*)&inp[(mg + 32) * LSTR + kk + u];
                    float4 a3 = *(const float4*)&inp[(mg + 48) * LSTR + kk + u];
                    acc0 += a0.x*w[u] + a0.y*w[u+1] + a0.z*w[u+2] + a0.w*w[u+3];
                    acc1 += a1.x*w[u] + a1.y*w[u+1] + a1.z*w[u+2] + a1.w*w[u+3];
                    acc2 += a2.x*w[u] + a2.y*w[u+1] + a2.z*w[u+2] + a2.w*w[u+3];
                    acc3 += a3.x*w[u] + a3.y*w[u+1] + a3.z*w[u+2] + a3.w*w[u+3];
                }
            }
            __syncthreads();
        }

        // exchange z across gate threads, then elementwise cell update
        zs[nl * 65 + mg +  0] = acc0;
        zs[nl * 65 + mg + 16] = acc1;
        zs[nl * 65 + mg + 32] = acc2;
        zs[nl * 65 + mg + 48] = acc3;
        __syncthreads();

        const int q = tid & 3;      // h-col offset within block's 4 columns
        const int m = tid >> 2;     // batch row 0..63
        const int hc = j0 + q;
        float zi = zs[(q +  0) * 65 + m] + bias[0 * NH + hc];
        float zf = zs[(q +  4) * 65 + m] + bias[1 * NH + hc];
        float zg = zs[(q +  8) * 65 + m] + bias[2 * NH + hc];
        float zo = zs[(q + 12) * 65 + m] + bias[3 * NH + hc];
        float iv = sigf(zi);
        float fv = sigf(zf);
        float gv = tanhf(zg);
        float ov = sigf(zo);
        const size_t cidx = (size_t)m * NH + hc;
        float cv = fv * cst[cidx] + iv * gv;
        cst[cidx] = cv;
        h_out[cidx] = ov * tanhf(cv);
    } else {
        // ---- projection block: out[:, pt, :] = relu(h_in @ Wo + bo) ----
        const int pblock = gates ? (bid - 256) : bid;  // 0..15
        const int pt = gates ? (t - 1) : t;
        if (pt < 0) return;                            // t==0: nothing to project yet
        const int o0 = pblock * 16;
        float acc0 = 0.f, acc1 = 0.f, acc2 = 0.f, acc3 = 0.f;

        for (int ci = 0; ci < 8; ++ci) {               // 8 * 128 = 1024 = H
            const int kbase = ci * KT;
            #pragma unroll
            for (int i = 0; i < 8; ++i) {
                const int idx = i * 256 + tid;
                const int row = idx >> 5;
                const int c4 = (idx & 31) * 4;
                *(float4*)&inp[row * LSTR + c4] =
                    *(const float4*)(h_in + (size_t)row * NH + kbase + c4);
            }
            __syncthreads();

            const float* Wp = Wo + (size_t)kbase * NDOUT + o0 + nl;
            for (int kk = 0; kk < KT; kk += 8) {
                float w[8];
                #pragma unroll
                for (int u = 0; u < 8; ++u) w[u] = Wp[(size_t)(kk + u) * NDOUT];
                #pragma unroll
                for (int u = 0; u < 8; u += 4) {
                    float4 a0 = *(const float4*)&inp[(mg +  0) * LSTR + kk + u];
                    float4 a1 = *(const float4*)&inp[(mg + 16) * LSTR + kk + u];
                    float4 a2 = *(const float4*)&inp[(mg + 32) * LSTR + kk + u];
                    float4 a3 = *(const float4*)&inp[(mg + 48) * LSTR + kk + u];
                    acc0 += a0.x*w[u] + a0.y*w[u+1] + a0.z*w[u+2] + a0.w*w[u+3];
                    acc1 += a1.x*w[u] + a1.y*w[u+1] + a1.z*w[u+2] + a1.w*w[u+3];
                    acc2 += a2.x*w[u] + a2.y*w[u+1] + a2.z*w[u+2] + a2.w*w[u+3];
                    acc3 += a3.x*w[u] + a3.y*w[u+1] + a3.z*w[u+2] + a3.w*w[u+3];
                }
            }
            __syncthreads();
        }

        const int o = o0 + nl;
        const float bb = bo[o];
        out[((size_t)(mg +  0) * NT + pt) * NDOUT + o] = fmaxf(acc0 + bb, 0.f);
        out[((size_t)(mg + 16) * NT + pt) * NDOUT + o] = fmaxf(acc1 + bb, 0.f);
        out[((size_t)(mg + 32) * NT + pt) * NDOUT + o] = fmaxf(acc2 + bb, 0.f);
        out[((size_t)(mg + 48) * NT + pt) * NDOUT + o] = fmaxf(acc3 + bb, 0.f);
    }
}

extern "C" void kernel_launch(void* const* d_in, const int* in_sizes, int n_in,
                              void* d_out, int out_size, void* d_ws, size_t ws_size,
                              hipStream_t stream) {
    const float* x  = (const float*)d_in[0];
    const float* Wx = (const float*)d_in[1];
    const float* Wh = (const float*)d_in[2];
    const float* b  = (const float*)d_in[3];
    const float* Wo = (const float*)d_in[4];
    const float* bo = (const float*)d_in[5];
    float* out = (float*)d_out;
    float* ws  = (float*)d_ws;

    float* h0 = ws;                 // [64*1024]
    float* h1 = ws + NB * NH;       // [64*1024]
    float* c  = ws + 2 * NB * NH;   // [64*1024]
    float* hb[2] = {h0, h1};

    // h0 and c must start at zero (ws is poisoned 0xAA each call)
    zero_kernel<<<(3 * NB * NH + 255) / 256, 256, 0, stream>>>(ws, 3 * NB * NH);

    for (int t = 0; t < NT; ++t) {
        lstm_step<<<272, 256, 0, stream>>>(x, Wx, Wh, b, Wo, bo,
                                           hb[t & 1], hb[(t + 1) & 1], c, out,
                                           t, 1);
    }
    // tail projection for t = 511 from h_512 (lives in hb[0])
    lstm_step<<<16, 256, 0, stream>>>(x, Wx, Wh, b, Wo, bo,
                                      hb[0], hb[1], c, out,
                                      NT - 1, 0);
}

// Round 2
// 17667.844 us; speedup vs baseline: 2.6817x; 2.6817x over previous
//
#include <hip/hip_runtime.h>
#include <math.h>

// Problem constants
#define NB 64      // batch
#define NT 512     // timesteps
#define NDIN 256   // input dim
#define NH 1024    // hidden
#define NG 4096    // 4*NH gate width
#define NDOUT 256  // output dim

// LDS strides (floats). 68 = 64 + 4 pad (keeps 16B alignment, spreads banks).
#define ASTR 68
#define WSTR 68
#define PWSTR 20

__device__ __forceinline__ float sigf(float v) { return 1.0f / (1.0f + expf(-v)); }

__global__ void zero_kernel(float* __restrict__ p, int n) {
    int i = blockIdx.x * 256 + threadIdx.x;
    if (i < n) p[i] = 0.0f;
}

// gates==1: blocks [0,256): z-GEMM splitK partials  zpart[ks][64][4096]
//           blocks [256,320): projection partials of h_{t-1} -> ppart[ks][64][256]
// gates==0: blocks [0,64): projection partials of h_prev (tail launch)
__global__ __launch_bounds__(256, 2) void zgemm(
    const float* __restrict__ x, const float* __restrict__ Wx,
    const float* __restrict__ Wh, const float* __restrict__ Wo,
    const float* __restrict__ h_prev,
    float* __restrict__ zpart, float* __restrict__ ppart,
    int t, int gates)
{
    __shared__ float lds[64 * ASTR + 64 * WSTR];
    const int tid = threadIdx.x;
    const int bid = blockIdx.x;

    if (gates && bid < 256) {
        // ---------------- z block: 64x64 tile, K-slice of 320 ----------------
        float* Al = lds;               // [64 rows][64 k] stride ASTR
        float* Wl = lds + 64 * ASTR;   // [64 k][64 cols] stride WSTR
        const int tile = bid >> 2;     // 0..63 -> gate-space col tile
        const int ks = bid & 3;        // K slice 0..3
        const int c0 = tile * 64;
        const int r0 = (tid >> 4) << 2;     // 4 rows per thread
        const int cofs = (tid & 15) << 2;   // 4 cols per thread

        float4 acc[4];
        #pragma unroll
        for (int i = 0; i < 4; ++i) acc[i] = make_float4(0.f, 0.f, 0.f, 0.f);

        float4 ra[4], rw[4];
        // prologue: load chunk 0 into registers
        {
            const int kbase = ks * 320;
            #pragma unroll
            for (int i = 0; i < 4; ++i) {
                int idx = i * 256 + tid;
                int row = idx >> 4, c4 = (idx & 15) << 2;
                int gk = kbase + c4;
                const float* src = (gk < NDIN)
                    ? (x + ((size_t)row * NT + t) * NDIN + gk)
                    : (h_prev + (size_t)row * NH + (gk - NDIN));
                ra[i] = *(const float4*)src;
            }
            #pragma unroll
            for (int i = 0; i < 4; ++i) {
                int idx = i * 256 + tid;
                int kr = idx >> 4, cc = (idx & 15) << 2;
                int gk = kbase + kr;
                const float* src = (gk < NDIN)
                    ? (Wx + (size_t)gk * NG + c0 + cc)
                    : (Wh + (size_t)(gk - NDIN) * NG + c0 + cc);
                rw[i] = *(const float4*)src;
            }
        }

        for (int ci = 0; ci < 5; ++ci) {
            // write staged registers to LDS
            #pragma unroll
            for (int i = 0; i < 4; ++i) {
                int idx = i * 256 + tid;
                int row = idx >> 4, c4 = (idx & 15) << 2;
                *(float4*)&Al[row * ASTR + c4] = ra[i];
            }
            #pragma unroll
            for (int i = 0; i < 4; ++i) {
                int idx = i * 256 + tid;
                int kr = idx >> 4, cc = (idx & 15) << 2;
                *(float4*)&Wl[kr * WSTR + cc] = rw[i];
            }
            __syncthreads();

            // prefetch next chunk (global -> regs), hidden under compute
            if (ci < 4) {
                const int kbase = ks * 320 + (ci + 1) * 64;
                #pragma unroll
                for (int i = 0; i < 4; ++i) {
                    int idx = i * 256 + tid;
                    int row = idx >> 4, c4 = (idx & 15) << 2;
                    int gk = kbase + c4;
                    const float* src = (gk < NDIN)
                        ? (x + ((size_t)row * NT + t) * NDIN + gk)
                        : (h_prev + (size_t)row * NH + (gk - NDIN));
                    ra[i] = *(const float4*)src;
                }
                #pragma unroll
                for (int i = 0; i < 4; ++i) {
                    int idx = i * 256 + tid;
                    int kr = idx >> 4, cc = (idx & 15) << 2;
                    int gk = kbase + kr;
                    const float* src = (gk < NDIN)
                        ? (Wx + (size_t)gk * NG + c0 + cc)
                        : (Wh + (size_t)(gk - NDIN) * NG + c0 + cc);
                    rw[i] = *(const float4*)src;
                }
            }

            // 64x64x64 microkernel: 4x4 outputs/thread, outer-product form
            #pragma unroll 4
            for (int k4 = 0; k4 < 64; k4 += 4) {
                float4 av[4], wv[4];
                #pragma unroll
                for (int i = 0; i < 4; ++i) av[i] = *(float4*)&Al[(r0 + i) * ASTR + k4];
                #pragma unroll
                for (int k = 0; k < 4; ++k) wv[k] = *(float4*)&Wl[(k4 + k) * WSTR + cofs];
                #pragma unroll
                for (int i = 0; i < 4; ++i) {
                    acc[i].x += av[i].x*wv[0].x + av[i].y*wv[1].x + av[i].z*wv[2].x + av[i].w*wv[3].x;
                    acc[i].y += av[i].x*wv[0].y + av[i].y*wv[1].y + av[i].z*wv[2].y + av[i].w*wv[3].y;
                    acc[i].z += av[i].x*wv[0].z + av[i].y*wv[1].z + av[i].z*wv[2].z + av[i].w*wv[3].z;
                    acc[i].w += av[i].x*wv[0].w + av[i].y*wv[1].w + av[i].z*wv[2].w + av[i].w*wv[3].w;
                }
            }
            __syncthreads();
        }

        #pragma unroll
        for (int i = 0; i < 4; ++i) {
            *(float4*)&zpart[((size_t)(ks * 64 + r0 + i)) * NG + c0 + cofs] = acc[i];
        }
    } else {
        // ---------------- projection block: 64x16 tile, K-slice of 256 -------
        const int pid = gates ? (bid - 256) : bid;
        if (gates && t == 0) return;   // no h_{t-1} yet
        float* Al = lds;
        float* Wl = lds + 64 * ASTR;   // [64 k][16 cols] stride PWSTR
        const int ct = pid & 15, ks = pid >> 4;
        const int c0 = ct * 16;
        const int tx = tid & 3, ty = tid >> 2;   // 1 row, 4 cols per thread
        float4 acc = make_float4(0.f, 0.f, 0.f, 0.f);

        for (int ci = 0; ci < 4; ++ci) {
            const int kbase = ks * 256 + ci * 64;
            #pragma unroll
            for (int i = 0; i < 4; ++i) {
                int idx = i * 256 + tid;
                int row = idx >> 4, c4 = (idx & 15) << 2;
                *(float4*)&Al[row * ASTR + c4] =
                    *(const float4*)(h_prev + (size_t)row * NH + kbase + c4);
            }
            {
                int kr = tid >> 2, cc = (tid & 3) << 2;
                *(float4*)&Wl[kr * PWSTR + cc] =
                    *(const float4*)(Wo + (size_t)(kbase + kr) * NDOUT + c0 + cc);
            }
            __syncthreads();

            #pragma unroll 4
            for (int k4 = 0; k4 < 64; k4 += 4) {
                float4 av = *(float4*)&Al[ty * ASTR + k4];
                float4 wv0 = *(float4*)&Wl[(k4 + 0) * PWSTR + tx * 4];
                float4 wv1 = *(float4*)&Wl[(k4 + 1) * PWSTR + tx * 4];
                float4 wv2 = *(float4*)&Wl[(k4 + 2) * PWSTR + tx * 4];
                float4 wv3 = *(float4*)&Wl[(k4 + 3) * PWSTR + tx * 4];
                acc.x += av.x*wv0.x + av.y*wv1.x + av.z*wv2.x + av.w*wv3.x;
                acc.y += av.x*wv0.y + av.y*wv1.y + av.z*wv2.y + av.w*wv3.y;
                acc.z += av.x*wv0.z + av.y*wv1.z + av.z*wv2.z + av.w*wv3.z;
                acc.w += av.x*wv0.w + av.y*wv1.w + av.z*wv2.w + av.w*wv3.w;
            }
            __syncthreads();
        }
        *(float4*)&ppart[((size_t)(ks * 64 + ty)) * NDOUT + c0 + tx * 4] = acc;
    }
}

// combine: sum 4 z K-slices, gates + cell update -> h_out, c;
// plus reduce projection partials of step pt -> out[:, pt, :].
__global__ __launch_bounds__(256) void combine(
    const float* __restrict__ zpart, const float* __restrict__ ppart,
    const float* __restrict__ bias, const float* __restrict__ bo,
    float* __restrict__ h_out, float* __restrict__ cst, float* __restrict__ out,
    int pt, int do_gates)
{
    const int e = blockIdx.x * 256 + threadIdx.x;
    if (do_gates) {
        const int m = e >> 10, j = e & 1023;
        float zi = 0.f, zf = 0.f, zg = 0.f, zo = 0.f;
        #pragma unroll
        for (int s = 0; s < 4; ++s) {
            const float* zp = zpart + ((size_t)(s * 64 + m)) * NG + j;
            zi += zp[0];
            zf += zp[NH];
            zg += zp[2 * NH];
            zo += zp[3 * NH];
        }
        float iv = sigf(zi + bias[j]);
        float fv = sigf(zf + bias[NH + j]);
        float gv = tanhf(zg + bias[2 * NH + j]);
        float ov = sigf(zo + bias[3 * NH + j]);
        const size_t ci = (size_t)m * NH + j;
        float cv = fv * cst[ci] + iv * gv;
        cst[ci] = cv;
        h_out[ci] = ov * tanhf(cv);
    }
    if (pt >= 0 && e < NB * NDOUT) {
        const int m = e >> 8, oc = e & 255;
        float v = bo[oc];
        #pragma unroll
        for (int s = 0; s < 4; ++s) v += ppart[((size_t)(s * 64 + m)) * NDOUT + oc];
        out[((size_t)m * NT + pt) * NDOUT + oc] = fmaxf(v, 0.f);
    }
}

extern "C" void kernel_launch(void* const* d_in, const int* in_sizes, int n_in,
                              void* d_out, int out_size, void* d_ws, size_t ws_size,
                              hipStream_t stream) {
    const float* x  = (const float*)d_in[0];
    const float* Wx = (const float*)d_in[1];
    const float* Wh = (const float*)d_in[2];
    const float* b  = (const float*)d_in[3];
    const float* Wo = (const float*)d_in[4];
    const float* bo = (const float*)d_in[5];
    float* out = (float*)d_out;
    float* ws  = (float*)d_ws;

    float* h0 = ws;                          // [64*1024]
    float* h1 = ws + NB * NH;                // [64*1024]
    float* c  = ws + 2 * NB * NH;            // [64*1024]
    float* zpart = ws + 3 * NB * NH;         // [4][64][4096] = 1M floats
    float* ppart = zpart + 4 * NB * NG;      // [4][64][256]
    float* hb[2] = {h0, h1};

    // h0, c must start at zero (ws re-poisoned 0xAA each call)
    zero_kernel<<<(3 * NB * NH + 255) / 256, 256, 0, stream>>>(ws, 3 * NB * NH);

    for (int t = 0; t < NT; ++t) {
        zgemm<<<320, 256, 0, stream>>>(x, Wx, Wh, Wo, hb[t & 1], zpart, ppart, t, 1);
        combine<<<256, 256, 0, stream>>>(zpart, ppart, b, bo,
                                         hb[(t + 1) & 1], c, out, t - 1, 1);
    }
    // tail: project h_511 (lives in hb[0]) -> out[:,511,:]
    zgemm<<<64, 256, 0, stream>>>(x, Wx, Wh, Wo, hb[0], zpart, ppart, NT, 0);
    combine<<<64, 256, 0, stream>>>(zpart, ppart, b, bo, hb[1], c, out, NT - 1, 0);
}

// Round 3
// 9722.430 us; speedup vs baseline: 4.8733x; 1.8172x over previous
//
#include <hip/hip_runtime.h>
#include <hip/hip_bf16.h>
#include <math.h>

#define NB 64
#define NT 512
#define NDIN 256
#define NH 1024
#define NG 4096
#define NDOUT 256

#define ASTR 68
#define WSTR 68
#define PWSTR 20

typedef __attribute__((ext_vector_type(8))) short short8;
typedef __attribute__((ext_vector_type(4))) float float4v;

__device__ __forceinline__ float sigf(float v) { return 1.0f / (1.0f + expf(-v)); }

__device__ __forceinline__ unsigned short bf_hi(float v, float* back) {
    __hip_bfloat16 b = __float2bfloat16(v);
    *back = __bfloat162float(b);
    union { __hip_bfloat16 b; unsigned short u; } cv; cv.b = b;
    return cv.u;
}

__global__ void zero_kernel(float* __restrict__ p, int n) {
    int i = blockIdx.x * 256 + threadIdx.x;
    if (i < n) p[i] = 0.0f;
}

// Pack W (= [Wx;Wh], K=1280 x N=4096) into B-fragment order, split hi/lo bf16.
// Frag layout: [nb(256)][ku(40)][lane(64)][j(8)]  where n=nb*16+(lane&15),
// k = ku*32 + (lane>>4)*8 + j.
__global__ void packW_kernel(const float* __restrict__ Wx, const float* __restrict__ Wh,
                             unsigned short* __restrict__ W0f, unsigned short* __restrict__ W1f) {
    int e = blockIdx.x * 256 + threadIdx.x;
    if (e >= 1280 * 4096) return;
    int k = e >> 12, n = e & 4095;
    float w = (k < NDIN) ? Wx[(size_t)k * NG + n] : Wh[(size_t)(k - NDIN) * NG + n];
    float back;
    unsigned short w0 = bf_hi(w, &back);
    float r = w - back;
    unsigned short w1 = bf_hi(r, &back);
    int nb = n >> 4, nl = n & 15, ku = k >> 5, kr = k & 31;
    int lane = (kr >> 3) * 16 + nl, j = kr & 7;
    size_t off = (((size_t)nb * 40 + ku) * 64 + lane) * 8 + j;
    W0f[off] = w0;
    W1f[off] = w1;
}

// Pack x ([64][512][256]) into A-fragment order, split hi/lo.
// Frag layout: [t][ku(8)][mb(4)][lane(64)][j(8)], m=mb*16+(lane&15),
// k = ku*32 + (lane>>4)*8 + j.
__global__ void packX_kernel(const float* __restrict__ x,
                             unsigned short* __restrict__ xf0, unsigned short* __restrict__ xf1) {
    int e = blockIdx.x * 256 + threadIdx.x;
    if (e >= NB * NT * NDIN) return;
    int k = e & 255, t = (e >> 8) & 511, m = e >> 17;
    float v = x[e];
    float back;
    unsigned short a0 = bf_hi(v, &back);
    float r = v - back;
    unsigned short a1 = bf_hi(r, &back);
    int ku = k >> 5, kr = k & 31, mb = m >> 4;
    int lane = (kr >> 3) * 16 + (m & 15), j = kr & 7;
    size_t off = ((((size_t)t * 8 + ku) * 4 + mb) * 64 + lane) * 8 + j;
    xf0[off] = a0;
    xf1[off] = a1;
}

// gates==1: blocks [0, 32*sK): MFMA z-GEMM splitK partials over 3-pass K-space
//           blocks [32*sK, +64): fp32 projection partials of h_t (round-2 code)
// gates==0: blocks [0,64): projection only (tail)
__global__ __launch_bounds__(256, 2) void zgemm(
    const unsigned short* __restrict__ W0f, const unsigned short* __restrict__ W1f,
    const unsigned short* __restrict__ xf0, const unsigned short* __restrict__ xf1,
    const unsigned short* __restrict__ hf,   // [v(2)][buf(2)][ku(32)][mb(4)][lane(64)][8]
    const float* __restrict__ h_prev, const float* __restrict__ Wo,
    float* __restrict__ zpart, float* __restrict__ ppart,
    int t, int sK, int U, int gates)
{
    __shared__ float lds[64 * ASTR + 64 * WSTR];
    const int tid = threadIdx.x;
    const int bid = blockIdx.x;
    const int ngate = gates ? 32 * sK : 0;

    if (bid < ngate) {
        const int lane = tid & 63;
        const int w = tid >> 6;
        const int ct = bid & 31;       // col-tile (128 cols)
        const int s = bid >> 5;        // K slice
        const int nb0 = ct * 8 + w * 2;
        const int hbuf = t & 1;

        float4v acc[4][2];
        #pragma unroll
        for (int mb = 0; mb < 4; ++mb)
            #pragma unroll
            for (int nl = 0; nl < 2; ++nl)
                acc[mb][nl] = (float4v){0.f, 0.f, 0.f, 0.f};

        const int u0 = s * U;
        for (int ui = 0; ui < U; ++ui) {
            const int u = u0 + ui;
            const int p = (u < 40) ? 0 : ((u < 80) ? 1 : 2);
            const int ku = u - p * 40;
            const unsigned short* Ab;
            if (ku < 8) {
                const unsigned short* xf = (p == 2) ? xf1 : xf0;
                Ab = xf + (((size_t)t * 8 + ku) * 4) * 512;
            } else {
                const int v = (p == 2) ? 1 : 0;
                Ab = hf + ((((size_t)v * 2 + hbuf) * 32 + (ku - 8)) * 4) * 512;
            }
            const unsigned short* Wf = (p == 1) ? W1f : W0f;

            short8 A[4], B[2];
            #pragma unroll
            for (int mb = 0; mb < 4; ++mb)
                A[mb] = *(const short8*)(Ab + (size_t)mb * 512 + lane * 8);
            #pragma unroll
            for (int nl = 0; nl < 2; ++nl)
                B[nl] = *(const short8*)(Wf + (((size_t)(nb0 + nl) * 40 + ku) * 64 + lane) * 8);

            #pragma unroll
            for (int mb = 0; mb < 4; ++mb)
                #pragma unroll
                for (int nl = 0; nl < 2; ++nl)
                    acc[mb][nl] = __builtin_amdgcn_mfma_f32_16x16x32_bf16(
                        A[mb], B[nl], acc[mb][nl], 0, 0, 0);
        }

        const int q = lane >> 4, nl16 = lane & 15;
        #pragma unroll
        for (int mb = 0; mb < 4; ++mb)
            #pragma unroll
            for (int nl = 0; nl < 2; ++nl)
                #pragma unroll
                for (int r = 0; r < 4; ++r) {
                    int m = mb * 16 + q * 4 + r;
                    int n = (nb0 + nl) * 16 + nl16;
                    zpart[((size_t)(s * 64 + m)) * NG + n] = acc[mb][nl][r];
                }
    } else {
        // ---------------- fp32 projection partials (round-2 verified code) ----
        const int pid = gates ? (bid - ngate) : bid;
        if (gates && t == 0) return;
        float* Al = lds;
        float* Wl = lds + 64 * ASTR;
        const int ct = pid & 15, ks = pid >> 4;
        const int c0 = ct * 16;
        const int tx = tid & 3, ty = tid >> 2;
        float4 acc = make_float4(0.f, 0.f, 0.f, 0.f);

        for (int ci = 0; ci < 4; ++ci) {
            const int kbase = ks * 256 + ci * 64;
            #pragma unroll
            for (int i = 0; i < 4; ++i) {
                int idx = i * 256 + tid;
                int row = idx >> 4, c4 = (idx & 15) << 2;
                *(float4*)&Al[row * ASTR + c4] =
                    *(const float4*)(h_prev + (size_t)row * NH + kbase + c4);
            }
            {
                int kr = tid >> 2, cc = (tid & 3) << 2;
                *(float4*)&Wl[kr * PWSTR + cc] =
                    *(const float4*)(Wo + (size_t)(kbase + kr) * NDOUT + c0 + cc);
            }
            __syncthreads();

            #pragma unroll 4
            for (int k4 = 0; k4 < 64; k4 += 4) {
                float4 av = *(float4*)&Al[ty * ASTR + k4];
                float4 wv0 = *(float4*)&Wl[(k4 + 0) * PWSTR + tx * 4];
                float4 wv1 = *(float4*)&Wl[(k4 + 1) * PWSTR + tx * 4];
                float4 wv2 = *(float4*)&Wl[(k4 + 2) * PWSTR + tx * 4];
                float4 wv3 = *(float4*)&Wl[(k4 + 3) * PWSTR + tx * 4];
                acc.x += av.x*wv0.x + av.y*wv1.x + av.z*wv2.x + av.w*wv3.x;
                acc.y += av.x*wv0.y + av.y*wv1.y + av.z*wv2.y + av.w*wv3.y;
                acc.z += av.x*wv0.z + av.y*wv1.z + av.z*wv2.z + av.w*wv3.z;
                acc.w += av.x*wv0.w + av.y*wv1.w + av.z*wv2.w + av.w*wv3.w;
            }
            __syncthreads();
        }
        *(float4*)&ppart[((size_t)(ks * 64 + ty)) * NDOUT + c0 + tx * 4] = acc;
    }
}

// Sum sK z-slices, gate math, cell update -> h (fp32 + bf16 hi/lo fragments);
// reduce projection partials of step pt -> out[:, pt, :].
__global__ __launch_bounds__(256) void combine(
    const float* __restrict__ zpart, const float* __restrict__ ppart,
    const float* __restrict__ bias, const float* __restrict__ bo,
    float* __restrict__ h_out, unsigned short* __restrict__ hf,
    float* __restrict__ cst, float* __restrict__ out,
    int pt, int do_gates, int sK, int nbuf)
{
    const int e = blockIdx.x * 256 + threadIdx.x;
    if (do_gates) {
        const int m = e >> 10, j = e & 1023;
        float zi = 0.f, zf = 0.f, zg = 0.f, zo = 0.f;
        for (int s = 0; s < sK; ++s) {
            const float* zp = zpart + ((size_t)(s * 64 + m)) * NG + j;
            zi += zp[0];
            zf += zp[NH];
            zg += zp[2 * NH];
            zo += zp[3 * NH];
        }
        float iv = sigf(zi + bias[j]);
        float fv = sigf(zf + bias[NH + j]);
        float gv = tanhf(zg + bias[2 * NH + j]);
        float ov = sigf(zo + bias[3 * NH + j]);
        const size_t ci = (size_t)m * NH + j;
        float cv = fv * cst[ci] + iv * gv;
        cst[ci] = cv;
        float hv = ov * tanhf(cv);
        h_out[ci] = hv;
        // bf16 hi/lo split into A-fragment order
        float back;
        unsigned short h0 = bf_hi(hv, &back);
        float r = hv - back;
        unsigned short h1 = bf_hi(r, &back);
        int ku = j >> 5, kr = j & 31, mb = m >> 4;
        int lane = (kr >> 3) * 16 + (m & 15), jj = kr & 7;
        size_t base = ((((size_t)0 * 2 + nbuf) * 32 + ku) * 4 + mb) * 512 + lane * 8 + jj;
        size_t vstride = (size_t)2 * 32 * 4 * 512;
        hf[base] = h0;
        hf[base + vstride] = h1;
    }
    if (pt >= 0 && e < NB * NDOUT) {
        const int m = e >> 8, oc = e & 255;
        float v = bo[oc];
        #pragma unroll
        for (int s = 0; s < 4; ++s) v += ppart[((size_t)(s * 64 + m)) * NDOUT + oc];
        out[((size_t)m * NT + pt) * NDOUT + oc] = fmaxf(v, 0.f);
    }
}

extern "C" void kernel_launch(void* const* d_in, const int* in_sizes, int n_in,
                              void* d_out, int out_size, void* d_ws, size_t ws_size,
                              hipStream_t stream) {
    const float* x  = (const float*)d_in[0];
    const float* Wx = (const float*)d_in[1];
    const float* Wh = (const float*)d_in[2];
    const float* b  = (const float*)d_in[3];
    const float* Wo = (const float*)d_in[4];
    const float* bo = (const float*)d_in[5];
    float* out = (float*)d_out;
    char* ws = (char*)d_ws;

    // ---- workspace layout (bytes) ----
    size_t off = 0;
    float* hb0   = (float*)(ws + off); off += NB * NH * 4;          // h fp32 buf0
    float* hb1   = (float*)(ws + off); off += NB * NH * 4;          // h fp32 buf1
    float* c     = (float*)(ws + off); off += NB * NH * 4;
    float* ppart = (float*)(ws + off); off += 4 * NB * NDOUT * 4;
    unsigned short* hf = (unsigned short*)(ws + off); off += (size_t)2 * 2 * 32 * 4 * 512 * 2;
    size_t zero_floats = off / 4;                                    // zero everything above
    unsigned short* W0f = (unsigned short*)(ws + off); off += (size_t)256 * 40 * 512 * 2;
    unsigned short* W1f = (unsigned short*)(ws + off); off += (size_t)256 * 40 * 512 * 2;
    unsigned short* xf0 = (unsigned short*)(ws + off); off += (size_t)512 * 8 * 4 * 512 * 2;
    unsigned short* xf1 = (unsigned short*)(ws + off); off += (size_t)512 * 8 * 4 * 512 * 2;
    float* zpart = (float*)(ws + off);                               // sK * 1 MB

    // splitK tier by available workspace
    int sK = 12;
    if (off + (size_t)12 * NB * NG * 4 > ws_size) sK = 6;
    const int U = 120 / sK;   // K-units (of 32) per slice over 3-pass space

    float* hb[2] = {hb0, hb1};

    zero_kernel<<<(int)((zero_floats + 255) / 256), 256, 0, stream>>>((float*)ws, (int)zero_floats);
    packW_kernel<<<(1280 * 4096 + 255) / 256, 256, 0, stream>>>(Wx, Wh, W0f, W1f);
    packX_kernel<<<(NB * NT * NDIN + 255) / 256, 256, 0, stream>>>(x, xf0, xf1);

    for (int t = 0; t < NT; ++t) {
        zgemm<<<32 * sK + 64, 256, 0, stream>>>(W0f, W1f, xf0, xf1, hf,
                                                hb[t & 1], Wo, zpart, ppart, t, sK, U, 1);
        combine<<<256, 256, 0, stream>>>(zpart, ppart, b, bo,
                                         hb[(t + 1) & 1], hf, c, out,
                                         t - 1, 1, sK, (t + 1) & 1);
    }
    // tail: project h_512 (in hb[0]) -> out[:,511,:]
    zgemm<<<64, 256, 0, stream>>>(W0f, W1f, xf0, xf1, hf,
                                  hb[0], Wo, zpart, ppart, NT, sK, U, 0);
    combine<<<64, 256, 0, stream>>>(zpart, ppart, b, bo,
                                    hb[1], hf, c, out, NT - 1, 0, sK, 0);
}